// Round 12
// baseline (281.302 us; speedup 1.0000x reference)
//
#include <hip/hip_runtime.h>
#include <hip/hip_fp16.h>

#define NN 100000
#define NE 1600000
#define NG 512
#define F  32

#define BSH    8                              // 256 dst-nodes per bucket
#define BNODES 256
#define NB     ((NN + BNODES - 1) / BNODES)   // 391
#define CAP    5120                           // slots/bucket (mean 4092, sigma 64 -> safe)
#define PCHUNK 4096
#define EPT    8                              // edges per thread (PCHUNK/512)
#define NWGP   ((NE + PCHUNK - 1) / PCHUNK)   // 391

// ---- partition: in-LDS counting sort per chunk -> coalesced bucket-run writes ----
__global__ void k_partition(const int* __restrict__ src, const int* __restrict__ dst,
                            int* __restrict__ cursor, int* __restrict__ part) {
    __shared__ int   s_cnt[NB];      // hist, then reused as rank counter
    __shared__ int   s_lstart[NB];
    __shared__ int   s_base[NB];
    __shared__ int   wsum[8];
    __shared__ int   lsort[PCHUNK];
    __shared__ short lbkt[PCHUNK];
    int tid = threadIdx.x;
    for (int i = tid; i < NB; i += 512) s_cnt[i] = 0;
    __syncthreads();
    int e0 = blockIdx.x * PCHUNK;
    int e1 = min(e0 + PCHUNK, NE);
    int pk[EPT]; short bk[EPT];
    int m = 0;
#pragma unroll
    for (int k = 0; k < EPT; ++k) {
        int e = e0 + tid + k * 512;
        if (e < e1) {
            int d = dst[e];
            pk[m] = (src[e] << 8) | (d & (BNODES - 1));
            bk[m] = (short)(d >> BSH);
            atomicAdd(&s_cnt[bk[m]], 1);
            ++m;
        }
    }
    __syncthreads();
    int cv = (tid < NB) ? s_cnt[tid] : 0;
    // wave-level inclusive scan (64 lanes), then cross-wave combine
    int v = cv;
#pragma unroll
    for (int o = 1; o < 64; o <<= 1) {
        int t = __shfl_up(v, o, 64);
        if ((tid & 63) >= o) v += t;
    }
    if ((tid & 63) == 63) wsum[tid >> 6] = v;
    __syncthreads();
    int add = 0;
    for (int w = 0; w < (tid >> 6); ++w) add += wsum[w];
    int excl = v + add - cv;
    if (tid < NB) {
        s_lstart[tid] = excl;
        if (cv) s_base[tid] = tid * CAP + atomicAdd(&cursor[tid], cv);
        s_cnt[tid] = 0;   // reuse as rank counter
    }
    __syncthreads();
    for (int k = 0; k < m; ++k) {
        int b = bk[k];
        int r = s_lstart[b] + atomicAdd(&s_cnt[b], 1);
        lsort[r] = pk[k];
        lbkt[r]  = (short)b;
    }
    __syncthreads();
    int cnt = e1 - e0;
    for (int i = tid; i < cnt; i += 512) {
        int b = lbkt[i];
        part[s_base[b] + (i - s_lstart[b])] = lsort[i];   // coalesced per-bucket runs
    }
}

// ---- fill2a: per-bucket histogram + wave-scan -> rowpack[(pos<<10)|deg], dinv, xd ----
__global__ void k_fill2a(const int* __restrict__ part, const int* __restrict__ cursor,
                         const float* __restrict__ x,
                         int* __restrict__ rowpack, float* __restrict__ dinv,
                         float4* __restrict__ xd) {
    __shared__ int cnt[BNODES];
    __shared__ int wsum[4];
    int b = blockIdx.x, tid = threadIdx.x;
    int node0 = b << BSH;
    int s0 = b * CAP, s1 = s0 + cursor[b];
    cnt[tid] = 0;
    __syncthreads();
    for (int i = s0 + tid; i < s1; i += 256) atomicAdd(&cnt[part[i] & (BNODES - 1)], 1);
    __syncthreads();
    int c = cnt[tid];
    int v = c;
#pragma unroll
    for (int o = 1; o < 64; o <<= 1) {
        int t = __shfl_up(v, o, 64);
        if ((tid & 63) >= o) v += t;
    }
    if ((tid & 63) == 63) wsum[tid >> 6] = v;
    __syncthreads();
    int add = 0;
    for (int w = 0; w < (tid >> 6); ++w) add += wsum[w];
    int excl = v + add - c;
    int n = node0 + tid;
    if (n < NN) {
        rowpack[n] = ((s0 + excl) << 10) | c;
        float d = rsqrtf((float)c + 1.0f);
        dinv[n] = d;
        xd[n] = make_float4(d * x[n * 3 + 0], d * x[n * 3 + 1], d * x[n * 3 + 2], d);
    }
}

// ---- fill2b: LDS-staged csr scatter + coalesced write-out + fused layer 1 ----
// g1[n] = dinv[n] * relu( (dinv[n]*(sum_e xd[s]+xd[n])) @ W1 + b1 )  fp16
__global__ void k_fill2b(const int* __restrict__ part, const int* __restrict__ cursor,
                         const int* __restrict__ rowpack, const float4* __restrict__ xd,
                         const float* __restrict__ W1, const float* __restrict__ b1,
                         int* __restrict__ csr, __half2* __restrict__ g1) {
    __shared__ int lcsr[CAP];
    __shared__ int off[BNODES];
    __shared__ float W1s[3 * F];
    __shared__ float b1s[F];
    int b = blockIdx.x, tid = threadIdx.x;
    int node0 = b << BSH;
    int s0 = b * CAP;
    int cnt = cursor[b];
    if (tid < 3 * F) W1s[tid] = W1[tid];
    if (tid < F) b1s[tid] = b1[tid];
    int n = node0 + tid;
    int pack = (n < NN) ? rowpack[n] : (s0 << 10);
    off[tid] = (pack >> 10) - s0;
    __syncthreads();
    for (int i = tid; i < cnt; i += 256) {
        int p = part[s0 + i];
        int pos = atomicAdd(&off[p & (BNODES - 1)], 1);
        lcsr[pos] = p >> 8;
    }
    __syncthreads();
    for (int i = tid; i < cnt; i += 256) csr[s0 + i] = lcsr[i];   // coalesced
    if (n < NN) {
        int deg = pack & 1023;
        int beg = (pack >> 10) - s0;
        int end = beg + deg;
        float ax = 0.0f, ay = 0.0f, az = 0.0f;
        int e = beg;
        for (; e + 7 < end; e += 8) {
#pragma unroll
            for (int u = 0; u < 8; ++u) {
                float4 v = xd[lcsr[e + u]];
                ax += v.x; ay += v.y; az += v.z;
            }
        }
        for (; e < end; ++e) {
            float4 v = xd[lcsr[e]];
            ax += v.x; ay += v.y; az += v.z;
        }
        float4 sf = xd[n];
        float dn = sf.w;
        float cx = dn * (ax + sf.x), cy = dn * (ay + sf.y), cz = dn * (az + sf.z);
        __half2 tmp[16];
#pragma unroll
        for (int j = 0; j < 16; ++j) {
            int f0 = 2 * j, f1 = 2 * j + 1;
            float v0 = cx * W1s[f0] + cy * W1s[F + f0] + cz * W1s[2 * F + f0] + b1s[f0];
            float v1 = cx * W1s[f1] + cy * W1s[F + f1] + cz * W1s[2 * F + f1] + b1s[f1];
            tmp[j] = __floats2half2_rn(dn * fmaxf(v0, 0.0f), dn * fmaxf(v1, 0.0f));
        }
        uint4* hv = (uint4*)(g1 + (size_t)n * 16);
        const uint4* tv = (const uint4*)tmp;
        hv[0] = tv[0]; hv[1] = tv[1]; hv[2] = tv[2]; hv[3] = tv[3];
    }
}

// ---- gather2p: gather g1 + fp32 t + proj2(W2)+relu + pool -> gsum; last block: head ----
__global__ void k_gather2p(const int* __restrict__ rowpack, const int* __restrict__ csr,
                           const __half2* __restrict__ g1, const float* __restrict__ dinv,
                           const int* __restrict__ batch,
                           const float* __restrict__ W2, const float* __restrict__ b2,
                           const float* __restrict__ Wl, const float* __restrict__ bl,
                           float* __restrict__ gsum, int* __restrict__ done,
                           float* __restrict__ out) {
    __shared__ float W2s[F * F];
    __shared__ float b2s[F];
    __shared__ float ts[16][F];
    __shared__ float hs[16][F];
    __shared__ int bat[16];
    __shared__ int slast;
    int tid = threadIdx.x;
    int nb = blockIdx.x * 16;
    for (int i = tid; i < F * F; i += 256) W2s[i] = W2[i];
    if (tid < F) b2s[tid] = b2[tid];
    if (tid < 16) bat[tid] = batch[nb + tid];
    int nl = tid >> 4, j = tid & 15;
    int n = nb + nl;
    {
        int pack = rowpack[n];
        int beg = pack >> 10, end = beg + (pack & 1023);
        float ax = 0.0f, ay = 0.0f;
        int e = beg;
        for (; e + 7 < end; e += 8) {
            int s0 = csr[e],     s1 = csr[e + 1], s2 = csr[e + 2], s3 = csr[e + 3];
            int s4 = csr[e + 4], s5 = csr[e + 5], s6 = csr[e + 6], s7 = csr[e + 7];
            float2 v0 = __half22float2(g1[s0 * 16 + j]);
            float2 v1 = __half22float2(g1[s1 * 16 + j]);
            float2 v2 = __half22float2(g1[s2 * 16 + j]);
            float2 v3 = __half22float2(g1[s3 * 16 + j]);
            float2 v4 = __half22float2(g1[s4 * 16 + j]);
            float2 v5 = __half22float2(g1[s5 * 16 + j]);
            float2 v6 = __half22float2(g1[s6 * 16 + j]);
            float2 v7 = __half22float2(g1[s7 * 16 + j]);
            ax += ((v0.x + v1.x) + (v2.x + v3.x)) + ((v4.x + v5.x) + (v6.x + v7.x));
            ay += ((v0.y + v1.y) + (v2.y + v3.y)) + ((v4.y + v5.y) + (v6.y + v7.y));
        }
        for (; e + 3 < end; e += 4) {
            int s0 = csr[e], s1 = csr[e + 1], s2 = csr[e + 2], s3 = csr[e + 3];
            float2 v0 = __half22float2(g1[s0 * 16 + j]);
            float2 v1 = __half22float2(g1[s1 * 16 + j]);
            float2 v2 = __half22float2(g1[s2 * 16 + j]);
            float2 v3 = __half22float2(g1[s3 * 16 + j]);
            ax += (v0.x + v1.x) + (v2.x + v3.x);
            ay += (v0.y + v1.y) + (v2.y + v3.y);
        }
        for (; e < end; ++e) {
            float2 v = __half22float2(g1[csr[e] * 16 + j]);
            ax += v.x; ay += v.y;
        }
        float dn = dinv[n];
        float2 sf = __half22float2(g1[n * 16 + j]);
        ts[nl][2 * j]     = dn * (ax + sf.x);
        ts[nl][2 * j + 1] = dn * (ay + sf.y);
    }
    __syncthreads();
    {
        int f = tid & 31;
        int nn0 = tid >> 5;           // 0..7
#pragma unroll
        for (int pass = 0; pass < 2; ++pass) {
            int nn = nn0 + pass * 8;
            float acc = b2s[f];
#pragma unroll
            for (int k = 0; k < F; ++k) acc += ts[nn][k] * W2s[k * F + f];
            hs[nn][f] = fmaxf(acc, 0.0f);
        }
    }
    __syncthreads();
    if (tid < F) {
        int g0 = bat[0], gmax = bat[15];
        for (int g = g0; g <= gmax; ++g) {
            float s = 0.0f;
#pragma unroll
            for (int i = 0; i < 16; ++i) if (bat[i] == g) s += hs[i][tid];
            atomicAdd(&gsum[g * F + tid], s);
        }
    }
    // ---- completion-counter: last block computes the head ----
    __syncthreads();
    if (tid == 0) {
        __threadfence();
        slast = (atomicAdd(done, 1) == (int)gridDim.x - 1) ? 1 : 0;
    }
    __syncthreads();
    if (slast) {
        __threadfence();
        for (int g = tid; g < NG; g += 256) {
            int lo = 0, hi = NN;
            while (lo < hi) { int m = (lo + hi) >> 1; if (batch[m] < g) lo = m + 1; else hi = m; }
            int s = lo;
            lo = 0; hi = NN;
            while (lo < hi) { int m = (lo + hi) >> 1; if (batch[m] < g + 1) lo = m + 1; else hi = m; }
            float inv = 1.0f / fmaxf((float)(lo - s), 1.0f);
            float a0 = 0.0f, a1 = 0.0f;
#pragma unroll
            for (int k = 0; k < F; ++k) {
                float mn = gsum[g * F + k] * inv;
                a0 += mn * Wl[k * 2 + 0];
                a1 += mn * Wl[k * 2 + 1];
            }
            out[g * 2 + 0] = a0 + bl[0];
            out[g * 2 + 1] = a1 + bl[1];
        }
    }
}

extern "C" void kernel_launch(void* const* d_in, const int* in_sizes, int n_in,
                              void* d_out, int out_size, void* d_ws, size_t ws_size,
                              hipStream_t stream) {
    const float* x     = (const float*)d_in[0];
    const int*   eidx  = (const int*)d_in[1];   // int32 per harness contract
    const int*   batch = (const int*)d_in[2];
    const float* W1    = (const float*)d_in[3];
    const float* b1    = (const float*)d_in[4];
    const float* W2    = (const float*)d_in[5];
    const float* b2    = (const float*)d_in[6];
    const float* Wl    = (const float*)d_in[7];
    const float* bl    = (const float*)d_in[8];
    float*       out   = (float*)d_out;

    const int* src = eidx;
    const int* dst = eidx + NE;

    // ---- workspace layout, 128B-aligned chunks ----
    char* base = (char*)d_ws;
    size_t off = 0;
    auto alloc = [&](size_t bytes) {
        void* p = base + off;
        off = (off + bytes + 127) & ~(size_t)127;
        return p;
    };
    // cursor + done + gsum contiguous -> single memset
    int*     cursor  = (int*)alloc((NB + 1) * sizeof(int) + (size_t)NG * F * sizeof(float));
    int*     done    = cursor + NB;
    float*   gsum    = (float*)(done + 1);
    int*     rowpack = (int*)alloc(NN * sizeof(int));
    int*     part    = (int*)alloc((size_t)NB * CAP * sizeof(int));
    int*     csr     = (int*)alloc((size_t)NB * CAP * sizeof(int));
    float*   dinv    = (float*)alloc(NN * sizeof(float));
    float4*  xd      = (float4*)alloc(NN * sizeof(float4));
    __half2* g1      = (__half2*)alloc((size_t)NN * 16 * sizeof(__half2));

    const int B = 256;
    const int gG16 = NN / 16;   // 6250, exact

    hipMemsetAsync(cursor, 0, (NB + 1) * sizeof(int) + (size_t)NG * F * sizeof(float), stream);

    // ---- CSR build ----
    k_partition<<<NWGP, 512, 0, stream>>>(src, dst, cursor, part);
    k_fill2a   <<<NB,   B,   0, stream>>>(part, cursor, x, rowpack, dinv, xd);
    k_fill2b   <<<NB,   B,   0, stream>>>(part, cursor, rowpack, xd, W1, b1, csr, g1);

    // ---- layer 2 gather + proj2 + relu + pool + head (fused, last-block head) ----
    k_gather2p<<<gG16, B, 0, stream>>>(rowpack, csr, g1, dinv, batch, W2, b2,
                                       Wl, bl, gsum, done, out);
}

// Round 13
// 164.601 us; speedup vs baseline: 1.7090x; 1.7090x over previous
//
#include <hip/hip_runtime.h>
#include <hip/hip_fp16.h>

#define NN 100000
#define NE 1600000
#define NG 512
#define F  32

#define BSH    8                              // 256 dst-nodes per bucket
#define BNODES 256
#define NB     ((NN + BNODES - 1) / BNODES)   // 391
#define CAP    5120                           // slots/bucket (mean 4092, sigma 64 -> safe)
#define PCHUNK 4096
#define EPT    8                              // edges per thread (PCHUNK/512)
#define NWGP   ((NE + PCHUNK - 1) / PCHUNK)   // 391

// ---- partition: in-LDS counting sort per chunk -> coalesced bucket-run writes ----
__global__ void k_partition(const int* __restrict__ src, const int* __restrict__ dst,
                            int* __restrict__ cursor, int* __restrict__ part) {
    __shared__ int   s_cnt[NB];      // hist, then reused as rank counter
    __shared__ int   s_lstart[NB];
    __shared__ int   s_base[NB];
    __shared__ int   wsum[8];
    __shared__ int   lsort[PCHUNK];
    __shared__ short lbkt[PCHUNK];
    int tid = threadIdx.x;
    for (int i = tid; i < NB; i += 512) s_cnt[i] = 0;
    __syncthreads();
    int e0 = blockIdx.x * PCHUNK;
    int e1 = min(e0 + PCHUNK, NE);
    int pk[EPT]; short bk[EPT];
    int m = 0;
#pragma unroll
    for (int k = 0; k < EPT; ++k) {
        int e = e0 + tid + k * 512;
        if (e < e1) {
            int d = dst[e];
            pk[m] = (src[e] << 8) | (d & (BNODES - 1));
            bk[m] = (short)(d >> BSH);
            atomicAdd(&s_cnt[bk[m]], 1);
            ++m;
        }
    }
    __syncthreads();
    int cv = (tid < NB) ? s_cnt[tid] : 0;
    int v = cv;
#pragma unroll
    for (int o = 1; o < 64; o <<= 1) {
        int t = __shfl_up(v, o, 64);
        if ((tid & 63) >= o) v += t;
    }
    if ((tid & 63) == 63) wsum[tid >> 6] = v;
    __syncthreads();
    int add = 0;
    for (int w = 0; w < (tid >> 6); ++w) add += wsum[w];
    int excl = v + add - cv;
    if (tid < NB) {
        s_lstart[tid] = excl;
        if (cv) s_base[tid] = tid * CAP + atomicAdd(&cursor[tid], cv);
        s_cnt[tid] = 0;   // reuse as rank counter
    }
    __syncthreads();
    for (int k = 0; k < m; ++k) {
        int b = bk[k];
        int r = s_lstart[b] + atomicAdd(&s_cnt[b], 1);
        lsort[r] = pk[k];
        lbkt[r]  = (short)b;
    }
    __syncthreads();
    int cnt = e1 - e0;
    for (int i = tid; i < cnt; i += 512) {
        int b = lbkt[i];
        part[s_base[b] + (i - s_lstart[b])] = lsort[i];   // coalesced per-bucket runs
    }
}

// ---- fill2a: per-bucket histogram + wave-scan -> rowpack[(pos<<10)|deg], dinv, xd ----
__global__ void k_fill2a(const int* __restrict__ part, const int* __restrict__ cursor,
                         const float* __restrict__ x,
                         int* __restrict__ rowpack, float* __restrict__ dinv,
                         float4* __restrict__ xd) {
    __shared__ int cnt[BNODES];
    __shared__ int wsum[4];
    int b = blockIdx.x, tid = threadIdx.x;
    int node0 = b << BSH;
    int s0 = b * CAP, s1 = s0 + cursor[b];
    cnt[tid] = 0;
    __syncthreads();
    for (int i = s0 + tid; i < s1; i += 256) atomicAdd(&cnt[part[i] & (BNODES - 1)], 1);
    __syncthreads();
    int c = cnt[tid];
    int v = c;
#pragma unroll
    for (int o = 1; o < 64; o <<= 1) {
        int t = __shfl_up(v, o, 64);
        if ((tid & 63) >= o) v += t;
    }
    if ((tid & 63) == 63) wsum[tid >> 6] = v;
    __syncthreads();
    int add = 0;
    for (int w = 0; w < (tid >> 6); ++w) add += wsum[w];
    int excl = v + add - c;
    int n = node0 + tid;
    if (n < NN) {
        rowpack[n] = ((s0 + excl) << 10) | c;
        float d = rsqrtf((float)c + 1.0f);
        dinv[n] = d;
        xd[n] = make_float4(d * x[n * 3 + 0], d * x[n * 3 + 1], d * x[n * 3 + 2], d);
    }
}

// ---- fill2b: LDS-staged csr scatter + coalesced write-out + fused layer 1 ----
// g1[n] = dinv[n] * relu( (dinv[n]*(sum_e xd[s]+xd[n])) @ W1 + b1 )  fp16
__global__ void k_fill2b(const int* __restrict__ part, const int* __restrict__ cursor,
                         const int* __restrict__ rowpack, const float4* __restrict__ xd,
                         const float* __restrict__ W1, const float* __restrict__ b1,
                         int* __restrict__ csr, __half2* __restrict__ g1) {
    __shared__ int lcsr[CAP];
    __shared__ int off[BNODES];
    __shared__ float W1s[3 * F];
    __shared__ float b1s[F];
    int b = blockIdx.x, tid = threadIdx.x;
    int node0 = b << BSH;
    int s0 = b * CAP;
    int cnt = cursor[b];
    if (tid < 3 * F) W1s[tid] = W1[tid];
    if (tid < F) b1s[tid] = b1[tid];
    int n = node0 + tid;
    int pack = (n < NN) ? rowpack[n] : (s0 << 10);
    off[tid] = (pack >> 10) - s0;
    __syncthreads();
    for (int i = tid; i < cnt; i += 256) {
        int p = part[s0 + i];
        int pos = atomicAdd(&off[p & (BNODES - 1)], 1);
        lcsr[pos] = p >> 8;
    }
    __syncthreads();
    for (int i = tid; i < cnt; i += 256) csr[s0 + i] = lcsr[i];   // coalesced
    if (n < NN) {
        int deg = pack & 1023;
        int beg = (pack >> 10) - s0;
        int end = beg + deg;
        float ax = 0.0f, ay = 0.0f, az = 0.0f;
        int e = beg;
        for (; e + 7 < end; e += 8) {
#pragma unroll
            for (int u = 0; u < 8; ++u) {
                float4 v = xd[lcsr[e + u]];
                ax += v.x; ay += v.y; az += v.z;
            }
        }
        for (; e < end; ++e) {
            float4 v = xd[lcsr[e]];
            ax += v.x; ay += v.y; az += v.z;
        }
        float4 sf = xd[n];
        float dn = sf.w;
        float cx = dn * (ax + sf.x), cy = dn * (ay + sf.y), cz = dn * (az + sf.z);
        __half2 tmp[16];
#pragma unroll
        for (int j = 0; j < 16; ++j) {
            int f0 = 2 * j, f1 = 2 * j + 1;
            float v0 = cx * W1s[f0] + cy * W1s[F + f0] + cz * W1s[2 * F + f0] + b1s[f0];
            float v1 = cx * W1s[f1] + cy * W1s[F + f1] + cz * W1s[2 * F + f1] + b1s[f1];
            tmp[j] = __floats2half2_rn(dn * fmaxf(v0, 0.0f), dn * fmaxf(v1, 0.0f));
        }
        uint4* hv = (uint4*)(g1 + (size_t)n * 16);
        const uint4* tv = (const uint4*)tmp;
        hv[0] = tv[0]; hv[1] = tv[1]; hv[2] = tv[2]; hv[3] = tv[3];
    }
}

// ---- gather2p: gather g1 + fp32 t + proj2(W2)+relu + per-block pool -> gsum ----
__global__ void k_gather2p(const int* __restrict__ rowpack, const int* __restrict__ csr,
                           const __half2* __restrict__ g1, const float* __restrict__ dinv,
                           const int* __restrict__ batch,
                           const float* __restrict__ W2, const float* __restrict__ b2,
                           float* __restrict__ gsum) {
    __shared__ float W2s[F * F];
    __shared__ float b2s[F];
    __shared__ float ts[16][F];
    __shared__ float hs[16][F];
    __shared__ int bat[16];
    int tid = threadIdx.x;
    int nb = blockIdx.x * 16;
    for (int i = tid; i < F * F; i += 256) W2s[i] = W2[i];
    if (tid < F) b2s[tid] = b2[tid];
    if (tid < 16) bat[tid] = batch[nb + tid];
    int nl = tid >> 4, j = tid & 15;
    int n = nb + nl;
    {
        int pack = rowpack[n];
        int beg = pack >> 10, end = beg + (pack & 1023);
        float ax = 0.0f, ay = 0.0f;
        int e = beg;
        for (; e + 7 < end; e += 8) {
            int s0 = csr[e],     s1 = csr[e + 1], s2 = csr[e + 2], s3 = csr[e + 3];
            int s4 = csr[e + 4], s5 = csr[e + 5], s6 = csr[e + 6], s7 = csr[e + 7];
            float2 v0 = __half22float2(g1[s0 * 16 + j]);
            float2 v1 = __half22float2(g1[s1 * 16 + j]);
            float2 v2 = __half22float2(g1[s2 * 16 + j]);
            float2 v3 = __half22float2(g1[s3 * 16 + j]);
            float2 v4 = __half22float2(g1[s4 * 16 + j]);
            float2 v5 = __half22float2(g1[s5 * 16 + j]);
            float2 v6 = __half22float2(g1[s6 * 16 + j]);
            float2 v7 = __half22float2(g1[s7 * 16 + j]);
            ax += ((v0.x + v1.x) + (v2.x + v3.x)) + ((v4.x + v5.x) + (v6.x + v7.x));
            ay += ((v0.y + v1.y) + (v2.y + v3.y)) + ((v4.y + v5.y) + (v6.y + v7.y));
        }
        for (; e + 3 < end; e += 4) {
            int s0 = csr[e], s1 = csr[e + 1], s2 = csr[e + 2], s3 = csr[e + 3];
            float2 v0 = __half22float2(g1[s0 * 16 + j]);
            float2 v1 = __half22float2(g1[s1 * 16 + j]);
            float2 v2 = __half22float2(g1[s2 * 16 + j]);
            float2 v3 = __half22float2(g1[s3 * 16 + j]);
            ax += (v0.x + v1.x) + (v2.x + v3.x);
            ay += (v0.y + v1.y) + (v2.y + v3.y);
        }
        for (; e < end; ++e) {
            float2 v = __half22float2(g1[csr[e] * 16 + j]);
            ax += v.x; ay += v.y;
        }
        float dn = dinv[n];
        float2 sf = __half22float2(g1[n * 16 + j]);
        ts[nl][2 * j]     = dn * (ax + sf.x);
        ts[nl][2 * j + 1] = dn * (ay + sf.y);
    }
    __syncthreads();
    {
        int f = tid & 31;
        int nn0 = tid >> 5;           // 0..7
#pragma unroll
        for (int pass = 0; pass < 2; ++pass) {
            int nn = nn0 + pass * 8;
            float acc = b2s[f];
#pragma unroll
            for (int k = 0; k < F; ++k) acc += ts[nn][k] * W2s[k * F + f];
            hs[nn][f] = fmaxf(acc, 0.0f);
        }
    }
    __syncthreads();
    if (tid < F) {
        int g0 = bat[0], gmax = bat[15];
        for (int g = g0; g <= gmax; ++g) {
            float s = 0.0f;
#pragma unroll
            for (int i = 0; i < 16; ++i) if (bat[i] == g) s += hs[i][tid];
            atomicAdd(&gsum[g * F + tid], s);
        }
    }
}

// ---- head: out[g] = (gsum[g]/max(cnt,1)) @ Wl + bl ----
__global__ void k_head(const float* __restrict__ gsum, const int* __restrict__ batch,
                       const float* __restrict__ Wl, const float* __restrict__ bl,
                       float* __restrict__ out) {
    int g = blockIdx.x * blockDim.x + threadIdx.x;
    if (g >= NG) return;
    int lo = 0, hi = NN;
    while (lo < hi) { int m = (lo + hi) >> 1; if (batch[m] < g) lo = m + 1; else hi = m; }
    int s = lo;
    lo = 0; hi = NN;
    while (lo < hi) { int m = (lo + hi) >> 1; if (batch[m] < g + 1) lo = m + 1; else hi = m; }
    float inv = 1.0f / fmaxf((float)(lo - s), 1.0f);
    float a0 = 0.0f, a1 = 0.0f;
#pragma unroll
    for (int k = 0; k < F; ++k) {
        float m = gsum[g * F + k] * inv;
        a0 += m * Wl[k * 2 + 0];
        a1 += m * Wl[k * 2 + 1];
    }
    out[g * 2 + 0] = a0 + bl[0];
    out[g * 2 + 1] = a1 + bl[1];
}

extern "C" void kernel_launch(void* const* d_in, const int* in_sizes, int n_in,
                              void* d_out, int out_size, void* d_ws, size_t ws_size,
                              hipStream_t stream) {
    const float* x     = (const float*)d_in[0];
    const int*   eidx  = (const int*)d_in[1];   // int32 per harness contract
    const int*   batch = (const int*)d_in[2];
    const float* W1    = (const float*)d_in[3];
    const float* b1    = (const float*)d_in[4];
    const float* W2    = (const float*)d_in[5];
    const float* b2    = (const float*)d_in[6];
    const float* Wl    = (const float*)d_in[7];
    const float* bl    = (const float*)d_in[8];
    float*       out   = (float*)d_out;

    const int* src = eidx;
    const int* dst = eidx + NE;

    // ---- workspace layout, 128B-aligned chunks ----
    char* base = (char*)d_ws;
    size_t off = 0;
    auto alloc = [&](size_t bytes) {
        void* p = base + off;
        off = (off + bytes + 127) & ~(size_t)127;
        return p;
    };
    // cursor + gsum contiguous -> single memset
    int*     cursor  = (int*)alloc(NB * sizeof(int) + (size_t)NG * F * sizeof(float));
    float*   gsum    = (float*)(cursor + NB);
    int*     rowpack = (int*)alloc(NN * sizeof(int));
    int*     part    = (int*)alloc((size_t)NB * CAP * sizeof(int));
    int*     csr     = (int*)alloc((size_t)NB * CAP * sizeof(int));
    float*   dinv    = (float*)alloc(NN * sizeof(float));
    float4*  xd      = (float4*)alloc(NN * sizeof(float4));
    __half2* g1      = (__half2*)alloc((size_t)NN * 16 * sizeof(__half2));

    const int B = 256;
    const int gG16 = NN / 16;   // 6250, exact

    hipMemsetAsync(cursor, 0, NB * sizeof(int) + (size_t)NG * F * sizeof(float), stream);

    // ---- CSR build ----
    k_partition<<<NWGP, 512, 0, stream>>>(src, dst, cursor, part);
    k_fill2a   <<<NB,   B,   0, stream>>>(part, cursor, x, rowpack, dinv, xd);
    k_fill2b   <<<NB,   B,   0, stream>>>(part, cursor, rowpack, xd, W1, b1, csr, g1);

    // ---- layer 2 gather + proj2 + relu + pool (fused) ----
    k_gather2p<<<gG16, B, 0, stream>>>(rowpack, csr, g1, dinv, batch, W2, b2, gsum);

    // ---- head ----
    k_head<<<(NG + B - 1) / B, B, 0, stream>>>(gsum, batch, Wl, bl, out);
}